// Round 3
// baseline (1650.151 us; speedup 1.0000x reference)
//
#include <hip/hip_runtime.h>

#define N_NODES 50000
#define N_EDGES 400000

typedef __bf16 bf16x8 __attribute__((ext_vector_type(8)));
typedef float f32x4 __attribute__((ext_vector_type(4)));

__device__ __forceinline__ float bflo(uint u){ union{uint i; float f;} v; v.i = u<<16; return v.f; }
__device__ __forceinline__ float bfhi(uint u){ union{uint i; float f;} v; v.i = u & 0xffff0000u; return v.f; }
__device__ __forceinline__ float bf2f(ushort u){ union{uint i; float f;} v; v.i = ((uint)u)<<16; return v.f; }
__device__ __forceinline__ ushort f2bf(float f){
  union{float f; uint i;} v; v.f = f;
  uint r = (v.i + 0x7fffu + ((v.i>>16)&1u))>>16;
  return (ushort)r;
}
__device__ __forceinline__ uint pack2(float a, float b){
  return (uint)f2bf(a) | ((uint)f2bf(b)<<16);
}

// ---------------- f32 -> bf16 convert ------------------------------------------
__global__ __launch_bounds__(256) void f32_to_bf16(
    const float* __restrict__ in, ushort* __restrict__ out, int n)
{
  int i = blockIdx.x*256 + threadIdx.x;
  if (i < n) out[i] = f2bf(in[i]);
}

// f32 -> bf16 with K padding (rows x Kin -> rows x Kout, zeros in pad)
__global__ __launch_bounds__(256) void convert_pad(
    const float* __restrict__ in, ushort* __restrict__ out,
    int rows, int Kin, int Kout)
{
  int i = blockIdx.x*256 + threadIdx.x;
  if (i >= rows*Kout) return;
  int r = i / Kout, c = i - r*Kout;
  out[i] = (c < Kin) ? f2bf(in[(size_t)r*Kin + c]) : (ushort)0;
}

// ---------------- LayerNorm: one wave per node, 2 channels/lane ----------------
__global__ __launch_bounds__(256) void ln_kernel(
    const float* __restrict__ x, const float* __restrict__ w,
    const float* __restrict__ b, ushort* __restrict__ xn)
{
  int n = blockIdx.x*4 + (threadIdx.x>>6);
  if (n >= N_NODES) return;
  int lane = threadIdx.x & 63;
  float2 xp = ((const float2*)x)[(size_t)n*64 + lane];
  float x0 = xp.x, x1 = xp.y;
  float s = x0 + x1, s2 = x0*x0 + x1*x1;
  #pragma unroll
  for (int off=1; off<64; off<<=1){ s += __shfl_xor(s,off); s2 += __shfl_xor(s2,off); }
  float mu  = s*(1.0f/128.0f);
  float var = s2*(1.0f/128.0f) - mu*mu;
  float inv = 1.0f/sqrtf(var + 1e-5f);
  float2 wp = ((const float2*)w)[lane];
  float2 bp = ((const float2*)b)[lane];
  float y0 = (x0-mu)*inv*wp.x + bp.x;
  float y1 = (x1-mu)*inv*wp.y + bp.y;
  ((uint*)xn)[(size_t)n*64 + lane] = pack2(y0, y1);
}

// ---------------- Counting sort by dst -----------------------------------------
__global__ __launch_bounds__(256) void hist_kernel(
    const int* __restrict__ ei, int* __restrict__ cnt)
{
  int e = blockIdx.x*256 + threadIdx.x;
  if (e < N_EDGES) atomicAdd(&cnt[ei[N_EDGES + e]], 1);
}

// single-block exclusive scan of cnt[N_NODES] -> offs[N_NODES+1], cursor copy
__global__ __launch_bounds__(1024) void scan_kernel(
    const int* __restrict__ cnt, int* __restrict__ offs, int* __restrict__ cursor)
{
  __shared__ int wsum[16];
  __shared__ int carry_s;
  int tid = threadIdx.x, lane = tid & 63, wid = tid >> 6;
  if (tid == 0) carry_s = 0;
  __syncthreads();
  for (int base = 0; base < N_NODES; base += 1024){
    int i = base + tid;
    int v = (i < N_NODES) ? cnt[i] : 0;
    int x = v;
    #pragma unroll
    for (int o=1;o<64;o<<=1){ int t=__shfl_up(x,o); if (lane>=o) x+=t; }
    if (lane == 63) wsum[wid] = x;
    __syncthreads();
    if (wid == 0){
      int ws = (lane < 16) ? wsum[lane] : 0;
      #pragma unroll
      for (int o=1;o<16;o<<=1){ int t=__shfl_up(ws,o); if (lane>=o) ws+=t; }
      if (lane < 16) wsum[lane] = ws;
    }
    __syncthreads();
    int wpre = (wid > 0) ? wsum[wid-1] : 0;
    int exc = x + wpre - v;
    int total = wsum[15];
    int o_ = carry_s + exc;
    if (i < N_NODES){ offs[i] = o_; cursor[i] = o_; }
    __syncthreads();
    if (tid == 0) carry_s += total;
    __syncthreads();
  }
  if (tid == 0) offs[N_NODES] = carry_s;
}

// scatter: perm (sorted->orig edge), srcs, dsts, ed = (r, d0, d1, d2)
__global__ __launch_bounds__(256) void scatter_kernel(
    const int* __restrict__ ei, const float* __restrict__ rij,
    const float* __restrict__ dij, int* __restrict__ cursor,
    int* __restrict__ perm, int* __restrict__ srcs, int* __restrict__ dsts,
    float4* __restrict__ ed)
{
  int e = blockIdx.x*256 + threadIdx.x;
  if (e >= N_EDGES) return;
  int d = ei[N_EDGES + e];
  int pos = atomicAdd(&cursor[d], 1);
  perm[pos] = e;
  srcs[pos] = ei[e];
  dsts[pos] = d;
  ed[pos] = make_float4(rij[e], dij[3*(size_t)e], dij[3*(size_t)e+1], dij[3*(size_t)e+2]);
}

#define LDP 40  // padded LDS row (bf16 elems)

// ---------------- dkv GEMM: silu(fij[perm] @ Wdkv^T + b) -----------------------
// A-panel staging: full 128-row x K=128 gathered f32->bf16 panel loaded ONCE
// (per-row 400B coalesced reads), all 4 k-slices kept in LDS. B streamed.
// XCD-swizzled 1-D grid: 4 col-blocks of the same row-block are adjacent on one
// XCD -> A gather re-reads hit L2.
__global__ __launch_bounds__(256) void dkv_gemm(
    int st, int len, const int* __restrict__ perm,
    const float* __restrict__ fij, const ushort* __restrict__ W,
    const float* __restrict__ bias, ushort* __restrict__ out)
{
  __shared__ int rowid[128];
  __shared__ ushort As4[4][128*LDP];
  __shared__ ushort Bs[128*LDP];
  const int tid = threadIdx.x;
  int nwg = gridDim.x;
  int id  = blockIdx.x;
  int q = nwg >> 3, r8 = nwg & 7;
  int xcd = id & 7, iq = id >> 3;
  int base = (xcd < r8) ? xcd*(q+1) : r8*(q+1) + (xcd - r8)*q;
  int L = base + iq;
  const int bx = L >> 2, by = L & 3;
  const int row0 = bx*128, col0 = by*128;
  const int wave = tid>>6, lane = tid&63;
  const int wm = (wave>>1)*64, wn = (wave&1)*64;
  const int lr = lane&15, lq = lane>>4;
  f32x4 acc[4][4] = {};

  if (tid < 128) rowid[tid] = (row0 + tid < len) ? perm[st + row0 + tid] : -1;
  __syncthreads();
  // gathered A panel: 128 rows x 64 uints (128 bf16 ch), K pad 100->128
  #pragma unroll
  for (int it=0; it<32; ++it){
    int idx = it*256 + tid;
    int rr = idx>>6, c = idx&63;
    int eo = rowid[rr];
    uint val = 0u;
    if (eo >= 0 && c < 50){
      float2 f = *(const float2*)(fij + (size_t)eo*100 + 2*c);
      val = pack2(f.x, f.y);
    }
    *(uint*)&As4[c>>4][rr*LDP + 2*(c&15)] = val;
  }
  for (int k0=0; k0<4; ++k0){
    #pragma unroll
    for (int rnd=0; rnd<2; rnd++){
      int e4 = (rnd*256 + tid)*8;
      int rr = e4>>5, c = e4&31;
      uint4 t = *(const uint4*)(W + (size_t)(col0+rr)*128 + k0*32 + c);
      *(uint4*)&Bs[rr*LDP + c] = t;
    }
    __syncthreads();
    bf16x8 af[4], bfr[4];
    #pragma unroll
    for (int i=0;i<4;i++) af[i]  = *(const bf16x8*)&As4[k0][(wm + i*16 + lr)*LDP + lq*8];
    #pragma unroll
    for (int i=0;i<4;i++) bfr[i] = *(const bf16x8*)&Bs[(wn + i*16 + lr)*LDP + lq*8];
    #pragma unroll
    for (int i=0;i<4;i++)
      #pragma unroll
      for (int j=0;j<4;j++)
        acc[i][j] = __builtin_amdgcn_mfma_f32_16x16x32_bf16(af[i], bfr[j], acc[i][j], 0,0,0);
    __syncthreads();
  }
  #pragma unroll
  for (int i=0;i<4;i++){
    int rowb = wm + i*16 + lq*4;
    #pragma unroll
    for (int j=0;j<4;j++){
      int c = col0 + wn + j*16 + lr;
      float bv = bias[c];
      #pragma unroll
      for (int rg=0; rg<4; rg++){
        int row = row0 + rowb + rg;
        if (row < len){
          float vv = acc[i][j][rg] + bv;
          vv = vv/(1.0f + __expf(-vv));
          out[(size_t)row*512 + c] = f2bf(vv);
        }
      }
    }
  }
}

// ---------------- Generic MFMA GEMM (A bf16): act(A[M,K] @ W[Nc,K]^T + b) ------
// MODEs: 0: bf16 store
//        6: Cf = vv*bf16(aux1)[(row/3)*Nc+c] + aux2f[row*Nc+c]   (dvec)
//        8: dual-B: Cf[row*Nc+c] = (acc1+b1)*(acc2+b2)           (prod for vdot)
template<int MODE>
__global__ __launch_bounds__(256) void gemm_bt(
    const ushort* __restrict__ A, const ushort* __restrict__ W,
    const ushort* __restrict__ W2,
    const float* __restrict__ bias, const float* __restrict__ bias2,
    void* Cptr, const void* aux1, void* aux2,
    int M, int K, int Nc)
{
  __shared__ ushort As[128*LDP];
  __shared__ ushort Bs[128*LDP];
  __shared__ ushort Bs2[(MODE==8) ? 128*LDP : 2];
  const int tid = threadIdx.x;
  const int row0 = blockIdx.x*128, col0 = blockIdx.y*128;
  const int wave = tid>>6, lane = tid&63;
  const int wm = (wave>>1)*64, wn = (wave&1)*64;
  const int lr = lane&15, lq = lane>>4;
  f32x4 acc[4][4] = {};
  f32x4 acc2[4][4] = {};

  for (int k0=0; k0<K; k0+=32){
    #pragma unroll
    for (int rnd=0; rnd<2; rnd++){
      int e4 = (rnd*256 + tid)*8;
      int r = e4>>5, c = e4&31;
      int gk = k0 + c;
      { // A tile
        int gr = row0 + r;
        if (gr < M){
          uint4 t = *(const uint4*)(A + (size_t)gr*K + gk);
          *(uint4*)&As[r*LDP + c] = t;
        } else {
          *(uint4*)&As[r*LDP + c] = make_uint4(0,0,0,0);
        }
      }
      { // B tile
        int gr = col0 + r;
        if (gr < Nc){
          uint4 t = *(const uint4*)(W + (size_t)gr*K + gk);
          *(uint4*)&Bs[r*LDP + c] = t;
        } else {
          *(uint4*)&Bs[r*LDP + c] = make_uint4(0,0,0,0);
        }
      }
      if (MODE==8){
        int gr = col0 + r;
        if (gr < Nc){
          uint4 t = *(const uint4*)(W2 + (size_t)gr*K + gk);
          *(uint4*)&Bs2[r*LDP + c] = t;
        } else {
          *(uint4*)&Bs2[r*LDP + c] = make_uint4(0,0,0,0);
        }
      }
    }
    __syncthreads();
    bf16x8 af[4], bfr[4];
    #pragma unroll
    for (int i=0;i<4;i++) af[i]  = *(const bf16x8*)&As[(wm + i*16 + lr)*LDP + lq*8];
    #pragma unroll
    for (int i=0;i<4;i++) bfr[i] = *(const bf16x8*)&Bs[(wn + i*16 + lr)*LDP + lq*8];
    #pragma unroll
    for (int i=0;i<4;i++)
      #pragma unroll
      for (int j=0;j<4;j++)
        acc[i][j] = __builtin_amdgcn_mfma_f32_16x16x32_bf16(af[i], bfr[j], acc[i][j], 0,0,0);
    if (MODE==8){
      bf16x8 bfr2[4];
      #pragma unroll
      for (int i=0;i<4;i++) bfr2[i] = *(const bf16x8*)&Bs2[(wn + i*16 + lr)*LDP + lq*8];
      #pragma unroll
      for (int i=0;i<4;i++)
        #pragma unroll
        for (int j=0;j<4;j++)
          acc2[i][j] = __builtin_amdgcn_mfma_f32_16x16x32_bf16(af[i], bfr2[j], acc2[i][j], 0,0,0);
    }
    __syncthreads();
  }

  const ushort* aux1b = (const ushort*)aux1;
  float* aux2f = (float*)aux2;

  #pragma unroll
  for (int i=0;i<4;i++){
    int rowb = row0 + wm + i*16 + lq*4;
    #pragma unroll
    for (int j=0;j<4;j++){
      int c = col0 + wn + j*16 + lr;
      float bv  = bias  ? bias[c]  : 0.0f;
      float bv2 = (MODE==8) ? bias2[c] : 0.0f;
      #pragma unroll
      for (int rg=0; rg<4; rg++){
        int row = rowb + rg;
        if (row < M){
          float vv = acc[i][j][rg] + bv;
          size_t idx = (size_t)row*Nc + c;
          if (MODE==0){
            ((ushort*)Cptr)[idx] = f2bf(vv);
          } else if (MODE==6){
            float o1 = bf2f(aux1b[(size_t)(row/3)*Nc + c]);
            ((float*)Cptr)[idx] = vv*o1 + aux2f[idx];
          } else if (MODE==8){
            float vv2 = acc2[i][j][rg] + bv2;
            ((float*)Cptr)[idx] = vv*vv2;
          }
        }
      }
    }
  }
}

// ---------------- Fused output GEMM: o1/o2/o3 from xagg, dx epilogue -----------
// A = xagg (f32, N x 128), W = Wo (384 x 128 bf16), bias = bo (384)
// dx = (prod[3n]+prod[3n+1]+prod[3n+2]) * o2 + o3 ; o1 -> bf16 store
__global__ __launch_bounds__(256) void final_gemm(
    const float* __restrict__ A, const ushort* __restrict__ W,
    const float* __restrict__ bias, const float* __restrict__ prod,
    float* __restrict__ dx, ushort* __restrict__ o1b)
{
  __shared__ ushort As[128*LDP];
  __shared__ ushort Bs[384*LDP];
  const int tid = threadIdx.x;
  const int row0 = blockIdx.x*128;
  const int wave = tid>>6, lane = tid&63;
  const int wm = (wave>>1)*64, wn = (wave&1)*64;
  const int lr = lane&15, lq = lane>>4;
  f32x4 acc[3][4][4] = {};

  for (int k0=0; k0<128; k0+=32){
    #pragma unroll
    for (int rnd=0; rnd<2; rnd++){
      int e4 = (rnd*256 + tid)*8;
      int r = e4>>5, c = e4&31;
      int gr = row0 + r;
      uint2 lo, hi;
      if (gr < N_NODES){
        const float* p = A + (size_t)gr*128 + k0 + c;
        float4 f0 = *(const float4*)p;
        float4 f1 = *(const float4*)(p+4);
        lo = make_uint2(pack2(f0.x,f0.y), pack2(f0.z,f0.w));
        hi = make_uint2(pack2(f1.x,f1.y), pack2(f1.z,f1.w));
      } else { lo = make_uint2(0,0); hi = make_uint2(0,0); }
      *(uint2*)&As[r*LDP + c]     = lo;
      *(uint2*)&As[r*LDP + c + 4] = hi;
    }
    #pragma unroll
    for (int rnd=0; rnd<6; rnd++){
      int e4 = (rnd*256 + tid)*8;
      int r = e4>>5, c = e4&31;
      uint4 t = *(const uint4*)(W + (size_t)r*128 + k0 + c);
      *(uint4*)&Bs[r*LDP + c] = t;
    }
    __syncthreads();
    bf16x8 af[4];
    #pragma unroll
    for (int i=0;i<4;i++) af[i] = *(const bf16x8*)&As[(wm + i*16 + lr)*LDP + lq*8];
    #pragma unroll
    for (int g=0; g<3; g++){
      bf16x8 bfr[4];
      #pragma unroll
      for (int i=0;i<4;i++) bfr[i] = *(const bf16x8*)&Bs[(g*128 + wn + i*16 + lr)*LDP + lq*8];
      #pragma unroll
      for (int i=0;i<4;i++)
        #pragma unroll
        for (int j=0;j<4;j++)
          acc[g][i][j] = __builtin_amdgcn_mfma_f32_16x16x32_bf16(af[i], bfr[j], acc[g][i][j], 0,0,0);
    }
    __syncthreads();
  }

  #pragma unroll
  for (int i=0;i<4;i++){
    int rowb = row0 + wm + i*16 + lq*4;
    #pragma unroll
    for (int j=0;j<4;j++){
      int c = wn + j*16 + lr;
      float b1 = bias[c], b2 = bias[128+c], b3 = bias[256+c];
      #pragma unroll
      for (int rg=0; rg<4; rg++){
        int row = rowb + rg;
        if (row < N_NODES){
          float o1 = acc[0][i][j][rg] + b1;
          float o2 = acc[1][i][j][rg] + b2;
          float o3 = acc[2][i][j][rg] + b3;
          size_t pb = (size_t)row*384 + c;
          float vd = prod[pb] + prod[pb+128] + prod[pb+256];
          dx[(size_t)row*128 + c] = vd*o2 + o3;
          o1b[(size_t)row*128 + c] = f2bf(o1);
        }
      }
    }
  }
}

// ---------------- Aggregation: wave per 16 sorted edge positions ---------------
// One-edge software pipeline: all per-edge gathers prefetched one iteration
// ahead; run-flush accumulation (one atomic set per dst run).
#define AGG_G 16

#define AGG_FLUSH() do{ \
    float* xrow = x_agg + (size_t)dcur*128; \
    atomicAdd(xrow+f0,   xa0); \
    atomicAdd(xrow+f0+1, xa1); \
    float* vrow = vec_agg + (size_t)dcur*384; \
    atomicAdd(vrow+f0,       vA0); atomicAdd(vrow+f0+1,     vA1); \
    atomicAdd(vrow+128+f0,   vB0); atomicAdd(vrow+128+f0+1, vB1); \
    atomicAdd(vrow+256+f0,   vC0); atomicAdd(vrow+256+f0+1, vC1); \
  }while(0)

__global__ __launch_bounds__(256) void agg_kernel(
    int st, int len,
    const int* __restrict__ dsts, const int* __restrict__ srcs,
    const float4* __restrict__ ed,
    const ushort* __restrict__ qk, const ushort* __restrict__ v,
    const ushort* __restrict__ vecb, const ushort* __restrict__ dkv,
    float* __restrict__ x_agg, float* __restrict__ vec_agg)
{
  int w = blockIdx.x*4 + (threadIdx.x>>6);
  int p0 = st + w*AGG_G;
  int pend = st + len;
  if (p0 >= pend) return;
  int p1 = p0 + AGG_G; if (p1 > pend) p1 = pend;
  int lane = threadIdx.x & 63;

  const uint* qk32  = (const uint*)qk;
  const uint* v32   = (const uint*)v;
  const uint* vec32 = (const uint*)vecb;
  const uint* dkv32 = (const uint*)dkv;
  int h  = lane>>3;
  int cb = h*24 + (lane&7);
  int f0 = 2*lane;

  int dcur = -1;
  uint qp = 0;
  float xa0=0.f, xa1=0.f;
  float vA0=0.f, vA1=0.f, vB0=0.f, vB1=0.f, vC0=0.f, vC1=0.f;

  // stage edge p0
  int src = srcs[p0], d = dsts[p0];
  float4 e = ed[p0];
  const uint* dr = dkv32 + (size_t)(p0-st)*256;
  uint kp  = qk32[(size_t)src*128 + 64 + lane];
  uint qpc = qk32[(size_t)d*128 + lane];
  uint dkp = dr[lane];
  uint dvx = dr[64+cb], dv1 = dr[64+cb+8], dv2 = dr[64+cb+16];
  size_t vr = (size_t)src*192;
  uint vx = v32[vr+cb], v1 = v32[vr+cb+8], v2 = v32[vr+cb+16];
  uint va = vec32[vr+lane], vbx = vec32[vr+64+lane], vc = vec32[vr+128+lane];

  for (int p=p0; p<p1; ++p){
    // prefetch edge p+1
    bool hasn = (p+1 < p1);
    int srcn=0, dn=0; float4 en=make_float4(0,0,0,0);
    uint kpn=0, qpcn=0, dkpn=0, dvxn=0, dv1n=0, dv2n=0;
    uint vxn=0, v1n=0, v2n=0, van=0, vbxn=0, vcn=0;
    if (hasn){
      srcn = srcs[p+1]; dn = dsts[p+1]; en = ed[p+1];
      const uint* drn = dkv32 + (size_t)(p+1-st)*256;
      kpn  = qk32[(size_t)srcn*128 + 64 + lane];
      qpcn = (dn != d) ? qk32[(size_t)dn*128 + lane] : qpc;
      dkpn = drn[lane];
      dvxn = drn[64+cb]; dv1n = drn[64+cb+8]; dv2n = drn[64+cb+16];
      size_t vrn = (size_t)srcn*192;
      vxn = v32[vrn+cb]; v1n = v32[vrn+cb+8]; v2n = v32[vrn+cb+16];
      van = vec32[vrn+lane]; vbxn = vec32[vrn+64+lane]; vcn = vec32[vrn+128+lane];
    }
    // run transition
    if (d != dcur){
      if (dcur >= 0) AGG_FLUSH();
      dcur = d;
      qp = qpc;
      xa0=xa1=vA0=vA1=vB0=vB1=vC0=vC1=0.f;
    }
    // compute current edge
    float s = bflo(qp)*bflo(kp)*bflo(dkp) + bfhi(qp)*bfhi(kp)*bfhi(dkp);
    s += __shfl_xor(s,1); s += __shfl_xor(s,2); s += __shfl_xor(s,4);
    float r = e.x;
    float cut = (r < 6.0f) ? 0.5f*(__cosf(r*0.52359877559829887f) + 1.0f) : 0.0f;
    float attn = (s/(1.0f + __expf(-s))) * cut;

    xa0 += bflo(vx)*bflo(dvx)*attn;
    xa1 += bfhi(vx)*bfhi(dvx)*attn;
    float v1m0 = bflo(v1)*bflo(dv1), v1m1 = bfhi(v1)*bfhi(dv1);
    float v2m0 = bflo(v2)*bflo(dv2), v2m1 = bfhi(v2)*bfhi(dv2);
    vA0 += bflo(va)*v1m0  + v2m0*e.y;  vA1 += bfhi(va)*v1m1  + v2m1*e.y;
    vB0 += bflo(vbx)*v1m0 + v2m0*e.z;  vB1 += bfhi(vbx)*v1m1 + v2m1*e.z;
    vC0 += bflo(vc)*v1m0  + v2m0*e.w;  vC1 += bfhi(vc)*v1m1  + v2m1*e.w;

    if (hasn){
      src=srcn; d=dn; e=en; kp=kpn; qpc=qpcn; dkp=dkpn;
      dvx=dvxn; dv1=dv1n; dv2=dv2n; vx=vxn; v1=v1n; v2=v2n;
      va=van; vbx=vbxn; vc=vcn;
    }
  }
  if (dcur >= 0) AGG_FLUSH();
}

extern "C" void kernel_launch(void* const* d_in, const int* in_sizes, int n_in,
                              void* d_out, int out_size, void* d_ws, size_t ws_size,
                              hipStream_t stream)
{
  (void)in_sizes; (void)n_in; (void)out_size;
  constexpr int Nn = N_NODES, Ee = N_EDGES;
  const float* x    = (const float*)d_in[0];
  const float* vec  = (const float*)d_in[1];
  const int*   eidx = (const int*)  d_in[2];
  const float* rij  = (const float*)d_in[3];
  const float* fij  = (const float*)d_in[4];
  const float* dij  = (const float*)d_in[5];
  const float* lnw  = (const float*)d_in[6];
  const float* lnb  = (const float*)d_in[7];
  const float* Wq   = (const float*)d_in[8];
  const float* bq   = (const float*)d_in[9];
  const float* Wk   = (const float*)d_in[10];
  const float* bk   = (const float*)d_in[11];
  const float* Wv   = (const float*)d_in[12];
  const float* bv   = (const float*)d_in[13];
  const float* Wvec = (const float*)d_in[14];
  const float* bvec = (const float*)d_in[15];
  const float* Wo   = (const float*)d_in[16];
  const float* bo   = (const float*)d_in[17];
  const float* Wdk  = (const float*)d_in[18];
  const float* bdk  = (const float*)d_in[19];
  const float* Wdv  = (const float*)d_in[20];
  const float* bdv  = (const float*)d_in[21];

  // ---- d_out (f32, 25.6M floats) time-multiplexing ----
  // [0 , 6.4M)  floats: qk combined bf16 during edge phase -> dx(f32)
  // [6.4M,25.6M) floats: vec_agg accumulator (f32) -> dvec (f32, same addresses)
  float*  outf = (float*)d_out;
  ushort* qkb  = (ushort*)d_out;                    // 25.6 MB
  float*  vagg = outf + (size_t)Nn*128;             // 3*Nn*128 f32

  // ---- workspace ----
  char* w = (char*)d_ws;
  size_t off = 0;
  auto alloc = [&](size_t bytes){ size_t o = off; off += (bytes + 255) & ~(size_t)255; return o; };

  ushort* WqkB  = (ushort*)(w + alloc(32768*2));    // Wq rows [0,128), Wk [128,256)
  ushort* WvB   = (ushort*)(w + alloc(49152*2));
  ushort* WvecB = (ushort*)(w + alloc(49152*2));
  ushort* WoB   = (ushort*)(w + alloc(49152*2));
  ushort* WdkvP = (ushort*)(w + alloc(512*128*2));  // Wdk|Wdv rows, K padded to 128
  float*  bqk   = (float*) (w + alloc(256*4));
  float*  bdkv  = (float*) (w + alloc(512*4));
  ushort* vecb  = (ushort*)(w + alloc((size_t)3*Nn*128*2));  // 38.4 MB
  ushort* vb    = (ushort*)(w + alloc((size_t)Nn*384*2));    // 38.4 MB
  float*  xagg  = (float*) (w + alloc((size_t)Nn*128*4));    // 25.6 MB
  ushort* o1b   = (ushort*)(w + alloc((size_t)Nn*128*2));    // 12.8 MB
  int*    cnt   = (int*)   (w + alloc((size_t)Nn*4));
  int*    offs  = (int*)   (w + alloc((size_t)(Nn+1)*4));
  int*    cursor= (int*)   (w + alloc((size_t)Nn*4));
  int*    perm  = (int*)   (w + alloc((size_t)Ee*4));
  int*    srcs  = (int*)   (w + alloc((size_t)Ee*4));
  int*    dsts  = (int*)   (w + alloc((size_t)Ee*4));
  float4* ed    = (float4*)(w + alloc((size_t)Ee*16));

  // scratch: xn (12.8 MB) -> dkv chunks (1024 B/edge) -> prod (76.8 MB)
  size_t sc_off = off;
  char*  sc = w + sc_off;
  ushort* xn = (ushort*)sc;
  long long chunkC = (ws_size > sc_off) ? (long long)((ws_size - sc_off) / 1024) : 128;
  if (chunkC > 98304) chunkC = 98304;
  chunkC &= ~127LL;
  if (chunkC < 128) chunkC = 128;
  ushort* dkvc = (ushort*)sc;
  float*  prod = (float*)sc;           // alive only after edge phase

  // ---- weight / vec conversion ----
  f32_to_bf16<<<(16384+255)/256, 256, 0, stream>>>(Wq,   WqkB,        16384);
  f32_to_bf16<<<(16384+255)/256, 256, 0, stream>>>(Wk,   WqkB+16384,  16384);
  f32_to_bf16<<<(49152+255)/256, 256, 0, stream>>>(Wv,   WvB,   49152);
  f32_to_bf16<<<(49152+255)/256, 256, 0, stream>>>(Wvec, WvecB, 49152);
  f32_to_bf16<<<(49152+255)/256, 256, 0, stream>>>(Wo,   WoB,   49152);
  convert_pad<<<(128*128+255)/256, 256, 0, stream>>>(Wdk, WdkvP,           128, 100, 128);
  convert_pad<<<(384*128+255)/256, 256, 0, stream>>>(Wdv, WdkvP + 128*128, 384, 100, 128);
  f32_to_bf16<<<(3*Nn*128+255)/256, 256, 0, stream>>>(vec, vecb, 3*Nn*128);
  hipMemcpyAsync(bqk,        bq,  128*4, hipMemcpyDeviceToDevice, stream);
  hipMemcpyAsync(bqk + 128,  bk,  128*4, hipMemcpyDeviceToDevice, stream);
  hipMemcpyAsync(bdkv,       bdk, 128*4, hipMemcpyDeviceToDevice, stream);
  hipMemcpyAsync(bdkv + 128, bdv, 384*4, hipMemcpyDeviceToDevice, stream);

  hipMemsetAsync(xagg, 0, (size_t)Nn*128*4, stream);
  hipMemsetAsync(vagg, 0, (size_t)3*Nn*128*4, stream);
  hipMemsetAsync(cnt,  0, (size_t)Nn*4, stream);

  // ---- counting sort of edges by dst ----
  hist_kernel<<<(Ee+255)/256, 256, 0, stream>>>(eidx, cnt);
  scan_kernel<<<1, 1024, 0, stream>>>(cnt, offs, cursor);
  scatter_kernel<<<(Ee+255)/256, 256, 0, stream>>>(eidx, rij, dij, cursor, perm, srcs, dsts, ed);

  ln_kernel<<<(Nn+3)/4, 256, 0, stream>>>(x, lnw, lnb, xn);

  // fused Q|K GEMM (Nc=256) and V GEMM
  gemm_bt<0><<<dim3((Nn+127)/128, 2), 256, 0, stream>>>(xn, WqkB, nullptr, bqk, nullptr, qkb, nullptr, nullptr, Nn, 128, 256);
  gemm_bt<0><<<dim3((Nn+127)/128, 3), 256, 0, stream>>>(xn, WvB,  nullptr, bv,  nullptr, vb,  nullptr, nullptr, Nn, 128, 384);

  // edge phase: panel-gather dkv GEMM (XCD-swizzled) -> pipelined agg
  for (int st = 0; st < Ee; st += (int)chunkC){
    int len = Ee - st; if (len > (int)chunkC) len = (int)chunkC;
    int nbx = (len+127)/128;
    dkv_gemm<<<nbx*4, 256, 0, stream>>>(st, len, perm, fij, WdkvP, bdkv, dkvc);
    int waves = (len + AGG_G - 1)/AGG_G;
    agg_kernel<<<(waves+3)/4, 256, 0, stream>>>(st, len, dsts, srcs, ed, qkb, vb, vecb, dkvc, xagg, vagg);
  }

  // prod[3n+a, c] = vp1*vp2  (no atomics; scratch reused, dkvc dead)
  gemm_bt<8><<<dim3((3*Nn+127)/128, 1), 256, 0, stream>>>(vecb, WvecB, WvecB + 128*128, bvec, bvec + 128, prod, nullptr, nullptr, 3*Nn, 128, 128);

  // fused: o1 -> o1b ; dx = (sum_a prod)*o2 + o3   (qkb dead, dx region free)
  final_gemm<<<(Nn+127)/128, 256, 0, stream>>>(xagg, WoB, bo, prod, outf, o1b);

  // dvec = vec3*o1 + vagg
  gemm_bt<6><<<dim3((3*Nn+127)/128, 1), 256, 0, stream>>>(vecb, WvecB + 256*128, nullptr, bvec + 256, nullptr, outf + (size_t)Nn*128, o1b, vagg, 3*Nn, 128, 128);
}